// Round 11
// baseline (121.774 us; speedup 1.0000x reference)
//
#include <hip/hip_runtime.h>
#include <math.h>

#define NQ   8192      // N queries per batch
#define NP   8192      // M points per batch
#define NF   128       // feature dim
#define NOUT 512       // output dim
#define NB   2         // batches
#define KNN  10
#define BNQ  (NB*NQ)   // 16384 total queries
#define QW   2         // queries per wave
#define CH   1024      // points per LDS chunk (16 KB)

typedef unsigned long long u64;
typedef unsigned short ushort_t;
typedef __attribute__((ext_vector_type(8))) short bf16x8;
typedef __attribute__((ext_vector_type(4))) float f32x4;

__device__ __forceinline__ u64 shfl64(u64 v, int src) {
  unsigned lo = (unsigned)__shfl((int)(unsigned)(v & 0xffffffffull), src, 64);
  unsigned hi = (unsigned)__shfl((int)(unsigned)(v >> 32), src, 64);
  return ((u64)hi << 32) | lo;
}
__device__ __forceinline__ u64 shflup64(u64 v) {
  unsigned lo = (unsigned)__shfl_up((int)(unsigned)(v & 0xffffffffull), 1, 64);
  unsigned hi = (unsigned)__shfl_up((int)(unsigned)(v >> 32), 1, 64);
  return ((u64)hi << 32) | lo;
}

// Shifted distance for SELECTION: d2' = p2 - 2 q.p  (3 fma). True d2 = d2'+q2.
__device__ __forceinline__ float dist2s(float m2x, float m2y, float m2z,
                                        float4 p) {
  return fmaf(m2x, p.x, fmaf(m2y, p.y, fmaf(m2z, p.z, p.w)));
}

// Monotone f32->u32 bit map: mono(a) < mono(b) (unsigned) <=> a < b (float).
__device__ __forceinline__ unsigned fmono(float f) {
  unsigned u = __float_as_uint(f);
  return u ^ ((unsigned)((int)u >> 31) | 0x80000000u);
}

// nextafter(f, +inf) for finite f incl. negatives and -0 (r7-verified).
__device__ __forceinline__ float nextupf(float f) {
  unsigned u = __float_as_uint(f);
  unsigned n = (u & 0x80000000u) ? ((u == 0x80000000u) ? 1u : u - 1u) : u + 1u;
  return __uint_as_float(n);
}

__device__ __forceinline__ float wmin64f(float v) {
#pragma unroll
  for (int off = 1; off < 64; off <<= 1)
    v = fminf(v, __shfl_xor(v, off, 64));
  return v;   // broadcast min across all 64 lanes
}

// round-to-nearest-even f32 -> bf16
__device__ __forceinline__ ushort_t f2bf(float x) {
  unsigned u = __float_as_uint(x);
  return (ushort_t)((u + 0x7FFFu + ((u >> 16) & 1u)) >> 16);
}

// ---------------------------------------------------------------------------
// Prep: pack points as (x,y,z,|p|^2); convert W[512][128] -> bf16 Wb[512][128]
// ---------------------------------------------------------------------------
__global__ __launch_bounds__(256) void prep_kernel(
    const float* __restrict__ gpcd, const float* __restrict__ W,
    float4* __restrict__ pts4, ushort_t* __restrict__ Wb)
{
  int tid = blockIdx.x * 256 + threadIdx.x;   // 0..65535
  if (tid < NB * NP) {
    const float* p = gpcd + (size_t)tid * 3;
    float x = p[0], y = p[1], z = p[2];
    float p2 = x * x + y * y + z * z;
    pts4[tid] = make_float4(x, y, z, p2);
  }
  Wb[tid] = f2bf(W[tid]);                     // 512*128 = 65536 elements
}

// ---------------------------------------------------------------------------
// Stage A+B (r10-verified logic; points now staged through LDS per block).
// Block = 4 waves, 8 queries. Per pass, 8 chunks of 1024 points are staged
// into a single 16 KB LDS buffer (reg-staged: issue loads for chunk c+1
// early, process chunk c from LDS, barrier, write, barrier). 4 waves share
// each staged chunk -> 4x less L1/L2 point traffic; ds_read_b128 with
// literal offsets replaces per-iter 64-bit global addressing.
// ---------------------------------------------------------------------------
__global__ __launch_bounds__(256) void knn_interp_kernel(
    const float* __restrict__ geometry, const float4* __restrict__ pts4,
    const float* __restrict__ features, ushort_t* __restrict__ Abf)
{
  __shared__ __align__(16) float4 Pl[CH];     // 16 KB chunk buffer

  const int lane = threadIdx.x & 63;
  const int wave = (blockIdx.x << 2) | (threadIdx.x >> 6);
  const int q0   = wave * QW;           // QW consecutive queries (same batch)
  const int b    = q0 >> 13;            // q0 / 8192 (block-uniform: 8 | 8192)
  const float4* __restrict__ P = pts4 + ((size_t)b << 13);
  const int tid4 = threadIdx.x << 2;    // this thread's 4-float4 staging slot

  float m2x[QW], m2y[QW], m2z[QW], q2[QW];
#pragma unroll
  for (int j = 0; j < QW; ++j) {
    const float* g = geometry + (size_t)(q0 + j) * 3;
    float x = g[0], y = g[1], z = g[2];
    q2[j]  = x * x + y * y + z * z;
    m2x[j] = -2.0f * x; m2y[j] = -2.0f * y; m2z[j] = -2.0f * z;
  }

  float4 st0, st1, st2, st3;            // staging registers (issue-early)

  // ---- prologue: stage chunk 0 ----
  {
    const float4* s = P + tid4;
    st0 = s[0]; st1 = s[1]; st2 = s[2]; st3 = s[3];
    float4* d = &Pl[tid4];
    d[0] = st0; d[1] = st1; d[2] = st2; d[3] = st3;
  }
  __syncthreads();

  // ---- pass 1: per-lane min of shifted d2' over LDS-staged chunks ----
  float lmin[QW];
#pragma unroll
  for (int j = 0; j < QW; ++j) lmin[j] = INFINITY;

  for (int c = 0; c < NP / CH; ++c) {
    if (c < NP / CH - 1) {              // issue next-chunk loads early
      const float4* s = P + ((c + 1) << 10) + tid4;
      st0 = s[0]; st1 = s[1]; st2 = s[2]; st3 = s[3];
    }
#pragma unroll
    for (int i = 0; i < CH / 64; ++i) {
      const float4 p = Pl[(i << 6) + lane];
#pragma unroll
      for (int j = 0; j < QW; ++j)
        lmin[j] = fminf(lmin[j], dist2s(m2x[j], m2y[j], m2z[j], p));
    }
    __syncthreads();                    // all waves done reading chunk c
    if (c < NP / CH - 1) {
      float4* d = &Pl[tid4];
      d[0] = st0; d[1] = st1; d[2] = st2; d[3] = st3;
      __syncthreads();                  // chunk c+1 visible
    }
  }

  // ---- stage chunk 0 for pass 2 (load early; write after knockout) ----
  {
    const float4* s = P + tid4;
    st0 = s[0]; st1 = s[1]; st2 = s[2]; st3 = s[3];
  }

  // ---- tau = 10th-smallest lane-min; theta = nextup(tau) ----
  float theta[QW];
#pragma unroll
  for (int j = 0; j < QW; ++j) {
    float lm  = lmin[j];
    float tau = 0.0f;
#pragma unroll
    for (int r = 0; r < KNN; ++r) {
      tau = wmin64f(lm);
      u64 mk = __ballot(lm == tau);
      int w  = __builtin_ctzll(mk);
      if (lane == w) lm = INFINITY;
    }
    theta[j] = nextupf(tau);            // include d2' == tau
  }

  u64   list[QW];
  float dl[QW];
#pragma unroll
  for (int j = 0; j < QW; ++j) {
    list[j] = 0xFFFFFFFFFFFFFFFFull;    // maximal key
    dl[j]   = INFINITY;
  }
  const float qnan = __builtin_nanf("");

  {
    float4* d = &Pl[tid4];
    d[0] = st0; d[1] = st1; d[2] = st2; d[3] = st3;
  }
  __syncthreads();

  // ---- pass 2: exact filtered insert (ascending index order) ----
  for (int c = 0; c < NP / CH; ++c) {
    if (c < NP / CH - 1) {              // issue next-chunk loads early
      const float4* s = P + ((c + 1) << 10) + tid4;
      st0 = s[0]; st1 = s[1]; st2 = s[2]; st3 = s[3];
    }
#pragma unroll 4
    for (int i = 0; i < CH / 64; ++i) {
      const float4 p = Pl[(i << 6) + lane];
      const int ib = (c << 10) + (i << 6);
#pragma unroll
      for (int j = 0; j < QW; ++j) {
        float d2 = dist2s(m2x[j], m2y[j], m2z[j], p);
        for (;;) {
          u64 mask = __ballot(d2 < theta[j]);
          if (!mask) break;
          int src = __builtin_ctzll(mask);
          float cd = __uint_as_float(
              (unsigned)__builtin_amdgcn_readlane(__float_as_int(d2), src));
          u64 kk = ((u64)fmono(cd) << 32) | (unsigned)(ib + src);
          u64   prev  = shflup64(list[j]);
          float prevd = __shfl(dl[j], lane - 1, 64);  // shfl_up by 1
          bool mylt = list[j] < kk;
          bool pins = (lane == 0) || (prev < kk);
          list[j] = mylt ? list[j] : (pins ? kk : prev);
          dl[j]   = mylt ? dl[j]  : (pins ? cd : prevd);
          // ascending-index processing: strict < vs raw dl[9] is exact;
          // min() so an underfull list (dl9=INF) can't lift theta
          theta[j] = fminf(theta[j], __uint_as_float(
              (unsigned)__builtin_amdgcn_readlane(__float_as_int(dl[j]), 9)));
          if (lane == src) d2 = qnan;   // processed: exits all future ballots
        }
      }
    }
    __syncthreads();                    // all waves done reading chunk c
    if (c < NP / CH - 1) {
      float4* d = &Pl[tid4];
      d[0] = st0; d[1] = st1; d[2] = st2; d[3] = st3;
      __syncthreads();                  // chunk c+1 visible
    }
  }

  // ---- weights + feature interpolation; bf16 row-major output ----
  const float* __restrict__ F = features + (size_t)b * NP * NF;
#pragma unroll
  for (int j = 0; j < QW; ++j) {
    float td2 = fmaxf(dl[j] + q2[j], 0.0f);       // back to true d2, clamped
    float w   = 1.0f / (sqrtf(td2) + 1e-8f);      // meaningful on lanes 0..9
    float wsum = 0.0f;
#pragma unroll
    for (int jj = 0; jj < KNN; ++jj) wsum += __shfl(w, jj, 64);

    float a0 = 0.0f, a1 = 0.0f;
#pragma unroll
    for (int jj = 0; jj < KNN; ++jj) {
      float wj = __shfl(w, jj, 64) / wsum;
      int  mi  = (int)(unsigned)(shfl64(list[j], jj) & 0xffffffffull);
      const float2 f2 = *(const float2*)(F + (size_t)mi * NF + (lane << 1));
      a0 = fmaf(wj, f2.x, a0);
      a1 = fmaf(wj, f2.y, a1);
    }
    unsigned pack = (unsigned)f2bf(a0) | ((unsigned)f2bf(a1) << 16);
    *(unsigned*)(Abf + (size_t)(q0 + j) * NF + (lane << 1)) = pack;
  }
}

// ---------------------------------------------------------------------------
// Stage C (MFMA, r9-verified): out[q][o] = sum_f A[q][f]*Wb[o][f] + bias[o]
// 16x16x32 bf16 MFMA. Block = 4 waves, tile M=128 x N=64; per wave 64x32.
// ---------------------------------------------------------------------------
__global__ __launch_bounds__(256) void proj_mfma(
    const ushort_t* __restrict__ Abf, const ushort_t* __restrict__ Wb,
    const float* __restrict__ bias, float* __restrict__ out)
{
  const int lane = threadIdx.x & 63;
  const int w    = threadIdx.x >> 6;        // wave 0..3
  const int mt   = blockIdx.x & 127;        // 128 m-blocks
  const int ot   = blockIdx.x >> 7;         // 8 o-blocks
  const int m0   = (mt << 7) + ((w & 1) << 6);   // wave's 64-row band
  const int o0   = (ot << 6) + ((w >> 1) << 5);  // wave's 32-col band
  const int r    = lane & 15;
  const int kg   = (lane >> 4) << 3;        // k offset 0,8,16,24

  f32x4 acc[4][2];
#pragma unroll
  for (int i = 0; i < 4; ++i)
#pragma unroll
    for (int jn = 0; jn < 2; ++jn) acc[i][jn] = (f32x4)0.0f;

#pragma unroll
  for (int ks = 0; ks < 4; ++ks) {
    const int k0 = (ks << 5) + kg;
    bf16x8 a[4], bb[2];
#pragma unroll
    for (int i = 0; i < 4; ++i)
      a[i] = *(const bf16x8*)(Abf + (size_t)(m0 + (i << 4) + r) * NF + k0);
#pragma unroll
    for (int jn = 0; jn < 2; ++jn)
      bb[jn] = *(const bf16x8*)(Wb + (size_t)(o0 + (jn << 4) + r) * NF + k0);
#pragma unroll
    for (int i = 0; i < 4; ++i)
#pragma unroll
      for (int jn = 0; jn < 2; ++jn)
        acc[i][jn] = __builtin_amdgcn_mfma_f32_16x16x32_bf16(
            a[i], bb[jn], acc[i][jn], 0, 0, 0);
  }

  const int crow = (lane >> 4) << 2;
#pragma unroll
  for (int jn = 0; jn < 2; ++jn) {
    const int oc = o0 + (jn << 4) + r;
    const float bv = bias[oc];
#pragma unroll
    for (int i = 0; i < 4; ++i) {
#pragma unroll
      for (int reg = 0; reg < 4; ++reg) {
        const int qm = m0 + (i << 4) + crow + reg;
        out[(size_t)qm * NOUT + oc] = acc[i][jn][reg] + bv;
      }
    }
  }
}

// ---------------------------------------------------------------------------
extern "C" void kernel_launch(void* const* d_in, const int* in_sizes, int n_in,
                              void* d_out, int out_size, void* d_ws, size_t ws_size,
                              hipStream_t stream) {
  const float* geometry = (const float*)d_in[0];   // [2,8192,3]
  const float* gpcd     = (const float*)d_in[1];   // [2,8192,3]
  const float* features = (const float*)d_in[2];   // [2,8192,128]
  const float* W        = (const float*)d_in[3];   // [512,128]
  const float* bias     = (const float*)d_in[4];   // [512]
  float* out = (float*)d_out;

  // workspace: Abf 4 MiB | pts4 256 KiB | Wb 128 KiB
  char*     ws   = (char*)d_ws;
  ushort_t* Abf  = (ushort_t*)ws;
  float4*   pts4 = (float4*)(ws + (size_t)BNQ * NF * 2);
  ushort_t* Wb   = (ushort_t*)(ws + (size_t)BNQ * NF * 2 + (size_t)NB * NP * 16);

  prep_kernel<<<256, 256, 0, stream>>>(gpcd, W, pts4, Wb);
  knn_interp_kernel<<<BNQ / (QW * 4), 256, 0, stream>>>(geometry, pts4, features, Abf);
  proj_mfma<<<(BNQ / 128) * (NOUT / 64), 256, 0, stream>>>(Abf, Wb, bias, out);
}